// Round 1
// baseline (374.868 us; speedup 1.0000x reference)
//
#include <hip/hip_runtime.h>
#include <stdint.h>
#include <stddef.h>

// GAT layer, N=12288, IN=512, OUT=256.
//   h = inp@W; s1=h@a1; s2=h@a2; e=lrelu(s1_i+s2_j); mask by adj; row softmax; out=elu(att@h)
// Key trick: softmax bound M_i = lrelu(s1_i + max_j s2_j) >= all row scores (lrelu monotone),
// so a single pass over adj computes both denominator and weighted sum (no rescale).
#define NN    12288
#define INF   512
#define OUTF  256
#define ALPHA 0.2f
#define LOG2E 1.44269504088896340736f

typedef __attribute__((ext_vector_type(4))) float        f32x4;
typedef __attribute__((ext_vector_type(8))) short        bf16x8;
typedef __attribute__((ext_vector_type(4))) unsigned int u32x4;
typedef __attribute__((ext_vector_type(4))) int          i32x4;

static __device__ __forceinline__ unsigned short f2bf(float f) {
  union { float f; unsigned u; } v; v.f = f;
  unsigned r = v.u + 0x7fffu + ((v.u >> 16) & 1u);   // RNE
  return (unsigned short)(r >> 16);
}
static __device__ __forceinline__ float bf2f(unsigned short s) {
  union { unsigned u; float f; } v; v.u = ((unsigned)s) << 16;
  return v.f;
}

// hT layout (pre-swizzled transposed h, bf16):
//   byte(col,k) = col*(NN*2) + (k>>6)*128 + (((k&63)*2) ^ ((col&7)<<4))
// so a linear 128B chunk copy into LDS yields the XOR-swizzled tile directly.

// ---------------- K1: h = inp@W (f32 accum), emit hT (bf16, transposed+swizzled) ----------
__global__ __launch_bounds__(256) void k1_gemm_h(const float* __restrict__ inp,
                                                 const float* __restrict__ W,
                                                 unsigned short* __restrict__ hT) {
  __shared__ float inp_s[32][36];
  __shared__ float W_s[32][256];
  const int t = threadIdx.x;
  const int row0 = blockIdx.x * 32;
  const int tx = t & 63, ty = t >> 6;
  f32x4 acc[8];
#pragma unroll
  for (int r = 0; r < 8; ++r) acc[r] = f32x4{0.f, 0.f, 0.f, 0.f};
  for (int kc = 0; kc < 16; ++kc) {
    {
      const int r = t >> 3, ko = (t & 7) * 4;
      *(f32x4*)&inp_s[r][ko] = *(const f32x4*)(inp + (size_t)(row0 + r) * INF + kc * 32 + ko);
    }
#pragma unroll
    for (int j = 0; j < 8; ++j) {
      const int r = j * 4 + ty;
      *(f32x4*)&W_s[r][tx * 4] = *(const f32x4*)(W + (size_t)(kc * 32 + r) * OUTF + tx * 4);
    }
    __syncthreads();
#pragma unroll 4
    for (int k = 0; k < 32; ++k) {
      const f32x4 wv = *(const f32x4*)&W_s[k][tx * 4];
#pragma unroll
      for (int rr = 0; rr < 8; ++rr) acc[rr] += inp_s[ty * 8 + rr][k] * wv;
    }
    __syncthreads();
  }
  // stage h tile into W_s (reuse) for transposed write
#pragma unroll
  for (int rr = 0; rr < 8; ++rr) *(f32x4*)&W_s[ty * 8 + rr][tx * 4] = acc[rr];
  __syncthreads();
  {
    const int col = t;  // this thread owns one hT column (= one h output feature)
    char* dst = (char*)hT + (size_t)col * (NN * 2) + (size_t)(row0 >> 6) * 128;
    const unsigned swz = (unsigned)((col & 7) << 4);
    const unsigned wbase = (unsigned)(row0 & 63) * 2;
#pragma unroll
    for (int s = 0; s < 4; ++s) {
      unsigned e0 = (unsigned)f2bf(W_s[s*8+0][col]) | ((unsigned)f2bf(W_s[s*8+1][col]) << 16);
      unsigned e1 = (unsigned)f2bf(W_s[s*8+2][col]) | ((unsigned)f2bf(W_s[s*8+3][col]) << 16);
      unsigned e2 = (unsigned)f2bf(W_s[s*8+4][col]) | ((unsigned)f2bf(W_s[s*8+5][col]) << 16);
      unsigned e3 = (unsigned)f2bf(W_s[s*8+6][col]) | ((unsigned)f2bf(W_s[s*8+7][col]) << 16);
      u32x4 p; p.x = e0; p.y = e1; p.z = e2; p.w = e3;
      *(u32x4*)(dst + ((wbase + (unsigned)s * 16) ^ swz)) = p;
    }
  }
}

// ---------------- K2: s1[i] = h[i]·a1, s2[i] = h[i]·a2 (from bf16 hT, coalesced) ----------
__global__ __launch_bounds__(256) void k2_s12(const unsigned short* __restrict__ hT,
                                              const float* __restrict__ a1,
                                              const float* __restrict__ a2,
                                              float* __restrict__ s1,
                                              float* __restrict__ s2) {
  const int i = blockIdx.x * 256 + threadIdx.x;  // 0..12287
  const size_t chunk = (size_t)(i >> 6) * 128;
  const unsigned within = (unsigned)(i & 63) * 2;
  float v1 = 0.f, v2 = 0.f;
  for (int d = 0; d < 256; ++d) {
    const unsigned off = within ^ ((unsigned)(d & 7) << 4);
    const unsigned short u =
        *(const unsigned short*)((const char*)hT + (size_t)d * (NN * 2) + chunk + off);
    const float f = bf2f(u);
    v1 += f * a1[d];
    v2 += f * a2[d];
  }
  s1[i] = v1; s2[i] = v2;
}

// ---------------- K3: S2MAX = max(s2) -----------------------------------------------------
__global__ __launch_bounds__(256) void k3_s2max(const float* __restrict__ s2,
                                                float* __restrict__ s2max) {
  __shared__ float red[256];
  const int t = threadIdx.x;
  float m = -3.0e38f;
  for (int j = t; j < NN; j += 256) m = fmaxf(m, s2[j]);
  red[t] = m;
  __syncthreads();
  for (int s = 128; s > 0; s >>= 1) {
    if (t < s) red[t] = fmaxf(red[t], red[t + s]);
    __syncthreads();
  }
  if (t == 0) s2max[0] = red[0];
}

// ---------------- K4: flash-style masked softmax-PV ---------------------------------------
// grid 384 = 192 row-blocks (64 rows) x 2 k-halves. 256 thr = 4 waves; wave = 64x64 output.
__global__ __launch_bounds__(256, 2) void k4_attn(const int* __restrict__ adj,
                                                  const unsigned short* __restrict__ hT,
                                                  const float* __restrict__ s1,
                                                  const float* __restrict__ s2,
                                                  const float* __restrict__ s2max,
                                                  float* __restrict__ accp,
                                                  float* __restrict__ denp) {
  __shared__ __align__(16) char B_lds[256 * 128];  // hT tile: 256 cols x 64 k (bf16, swizzled)
  __shared__ __align__(16) char w_lds[64 * 128];   // weight tile: 64 rows x 64 k (bf16, swizzled)
  const int t = threadIdx.x;
  const int w = t >> 6, l = t & 63;
  const int rb = blockIdx.x >> 1, half = blockIdx.x & 1;
  const int row0 = rb * 64;
  const int kstart = half * (NN / 2);

  const float S2MAX = s2max[0];
  // w-tile compute assignment: lane owns row w*16+(l>>2), k-quarter (l&3)*16
  const int wrow = w * 16 + (l >> 2);
  const int wrow_g = row0 + wrow;
  const int k0 = (l & 3) * 16;
  const float s1v = s1[wrow_g];
  const float tup = s1v + S2MAX;
  const float M = tup > 0.f ? tup : ALPHA * tup;  // per-row score upper bound
  float dsum = 0.f;

  f32x4 acc[4][4];
#pragma unroll
  for (int i = 0; i < 4; ++i)
#pragma unroll
    for (int j = 0; j < 4; ++j) acc[i][j] = f32x4{0.f, 0.f, 0.f, 0.f};

  const int* adjp = adj + (size_t)wrow_g * NN + kstart + k0;
  const float* s2p = s2 + kstart + k0;
  char* const wdst = w_lds + wrow * 128;
  const unsigned wswz = (unsigned)((wrow & 7) << 4);

  for (int it = 0; it < (NN / 2) / 64; ++it) {  // 96 iters
    __syncthreads();  // prior tile's LDS reads complete
    // stage B tile (32 KB) direct-to-LDS; pre-swizzled source -> swizzled LDS content
    {
      const size_t kb2 = (size_t)(kstart + it * 64) * 2;
#pragma unroll
      for (int s = 0; s < 8; ++s) {
        const int base = s * 256 + (w << 6);  // wave-uniform
        const int idx = base + l;
        const char* src = (const char*)hT + (size_t)(idx >> 3) * (NN * 2) + kb2 +
                          (size_t)(idx & 7) * 16;
        __builtin_amdgcn_global_load_lds(
            (const __attribute__((address_space(1))) unsigned int*)src,
            (__attribute__((address_space(3))) unsigned int*)(B_lds + (size_t)base * 16),
            16, 0, 0);
      }
    }
    // compute w tile: 16 scores per lane
    {
      int aarr[16]; float sarr[16];
      *(i32x4*)(&aarr[0])  = *(const i32x4*)(adjp + 0);
      *(i32x4*)(&aarr[4])  = *(const i32x4*)(adjp + 4);
      *(i32x4*)(&aarr[8])  = *(const i32x4*)(adjp + 8);
      *(i32x4*)(&aarr[12]) = *(const i32x4*)(adjp + 12);
      *(f32x4*)(&sarr[0])  = *(const f32x4*)(s2p + 0);
      *(f32x4*)(&sarr[4])  = *(const f32x4*)(s2p + 4);
      *(f32x4*)(&sarr[8])  = *(const f32x4*)(s2p + 8);
      *(f32x4*)(&sarr[12]) = *(const f32x4*)(s2p + 12);
      unsigned pk[8];
#pragma unroll
      for (int q = 0; q < 8; ++q) {
        unsigned short us[2];
#pragma unroll
        for (int hh = 0; hh < 2; ++hh) {
          const int j = q * 2 + hh;
          const float tt = s1v + sarr[j];
          const float e = tt > 0.f ? tt : ALPHA * tt;
          float wv = 0.f;
          if (aarr[j] != 0) wv = exp2f((e - M) * LOG2E);
          us[hh] = f2bf(wv);
          dsum += bf2f(us[hh]);  // denominator from the *rounded* weights
        }
        pk[q] = (unsigned)us[0] | ((unsigned)us[1] << 16);
      }
      u32x4 p0; p0.x = pk[0]; p0.y = pk[1]; p0.z = pk[2]; p0.w = pk[3];
      u32x4 p1; p1.x = pk[4]; p1.y = pk[5]; p1.z = pk[6]; p1.w = pk[7];
      *(u32x4*)(wdst + (((unsigned)(k0 * 2)) ^ wswz)) = p0;
      *(u32x4*)(wdst + (((unsigned)(k0 * 2 + 16)) ^ wswz)) = p1;
      adjp += 64; s2p += 64;
    }
    __syncthreads();  // drains vmcnt(0): B tile + w tile ready
    // MFMA: wave w -> cols w*64..+63, all 64 rows
#pragma unroll
    for (int kt = 0; kt < 2; ++kt) {
      const unsigned kbyte = (unsigned)((kt * 32 + (l >> 4) * 8) * 2);
      bf16x8 af[4], bfr[4];
#pragma unroll
      for (int rt = 0; rt < 4; ++rt) {
        const int row = rt * 16 + (l & 15);
        af[rt] = *(const bf16x8*)(w_lds + row * 128 + (kbyte ^ ((unsigned)((row & 7) << 4))));
      }
#pragma unroll
      for (int ct = 0; ct < 4; ++ct) {
        const int col = (w << 6) + ct * 16 + (l & 15);
        bfr[ct] = *(const bf16x8*)(B_lds + col * 128 + (kbyte ^ ((unsigned)((col & 7) << 4))));
      }
#pragma unroll
      for (int rt = 0; rt < 4; ++rt)
#pragma unroll
        for (int ct = 0; ct < 4; ++ct)
          acc[rt][ct] = __builtin_amdgcn_mfma_f32_16x16x32_bf16(af[rt], bfr[ct], acc[rt][ct],
                                                                0, 0, 0);
    }
  }
  // denominator: reduce the 4 k-quarter lanes of each row
  dsum += __shfl_xor(dsum, 1);
  dsum += __shfl_xor(dsum, 2);
  if ((l & 3) == 0) denp[(size_t)half * NN + wrow_g] = dsum;
  // partial accumulator write (f32)
  float* ap = accp + (size_t)half * NN * OUTF;
#pragma unroll
  for (int rt = 0; rt < 4; ++rt) {
    const int row = row0 + rt * 16 + ((l >> 4) << 2);
#pragma unroll
    for (int ct = 0; ct < 4; ++ct) {
      const int col = (w << 6) + ct * 16 + (l & 15);
#pragma unroll
      for (int j = 0; j < 4; ++j)
        ap[(size_t)(row + j) * OUTF + col] = acc[rt][ct][j];
    }
  }
}

// ---------------- K5: combine halves, divide, ELU -----------------------------------------
__global__ __launch_bounds__(256) void k5_combine(const float* __restrict__ accp,
                                                  const float* __restrict__ denp,
                                                  float* __restrict__ out) {
  const int idx = blockIdx.x * 256 + threadIdx.x;  // each handles 4 floats
  const int row = idx >> 6;
  const f32x4 a = *(const f32x4*)(accp + (size_t)idx * 4);
  const f32x4 b = *(const f32x4*)(accp + (size_t)NN * OUTF + (size_t)idx * 4);
  const float d = denp[row] + denp[NN + row];
  const float inv = 1.f / d;
  f32x4 v = (a + b) * inv;
  f32x4 r;
#pragma unroll
  for (int j = 0; j < 4; ++j) {
    const float x = v[j];
    r[j] = x > 0.f ? x : (__expf(x) - 1.f);
  }
  *(f32x4*)(out + (size_t)idx * 4) = r;
}

// ---------------- launch -------------------------------------------------------------------
extern "C" void kernel_launch(void* const* d_in, const int* in_sizes, int n_in,
                              void* d_out, int out_size, void* d_ws, size_t ws_size,
                              hipStream_t stream) {
  const float* inp = (const float*)d_in[0];
  const int*   adj = (const int*)d_in[1];
  const float* W   = (const float*)d_in[2];
  const float* a1  = (const float*)d_in[3];
  const float* a2  = (const float*)d_in[4];
  float* out = (float*)d_out;
  char* ws = (char*)d_ws;

  // ws layout (~30.2 MiB total)
  unsigned short* hT  = (unsigned short*)(ws + 0);          // 6,291,456 B
  float* s1   = (float*)(ws + 6291456);                     //    49,152 B
  float* s2   = (float*)(ws + 6340608);                     //    49,152 B
  float* s2m  = (float*)(ws + 6389760);                     //       256 B
  float* accp = (float*)(ws + 6390016);                     // 25,165,824 B
  float* denp = (float*)(ws + 31555840);                    //    98,304 B

  k1_gemm_h<<<dim3(NN / 32), dim3(256), 0, stream>>>(inp, W, hT);
  k2_s12<<<dim3(NN / 256), dim3(256), 0, stream>>>(hT, a1, a2, s1, s2);
  k3_s2max<<<dim3(1), dim3(256), 0, stream>>>(s2, s2m);
  k4_attn<<<dim3((NN / 64) * 2), dim3(256), 0, stream>>>(adj, hT, s1, s2, s2m, accp, denp);
  k5_combine<<<dim3(NN * OUTF / 1024), dim3(256), 0, stream>>>(accp, denp, out);
}